// Round 1
// baseline (2951.634 us; speedup 1.0000x reference)
//
#include <hip/hip_runtime.h>

#define D 128
#define NODES_PER_BLOCK 32

// ---------------------------------------------------------------------------
// Kernel 1: edge scatter-add.  32 threads per edge, each handles a float4.
// agg[dst] += x[src]  via f32 global atomics (device scope).
// ---------------------------------------------------------------------------
__global__ __launch_bounds__(256) void scatter_kernel(
    const float* __restrict__ x, const int* __restrict__ ei,
    float* __restrict__ agg, int E)
{
    int gid  = blockIdx.x * 256 + threadIdx.x;
    int e    = gid >> 5;          // edge id
    int lane = gid & 31;          // which float4 of the 128-float row
    if (e >= E) return;
    int s = ei[e];                // src
    int d = ei[E + e];            // dst
    float4 v = ((const float4*)(x + (long long)s * D))[lane];
    float* a = agg + (long long)d * D + lane * 4;
    atomicAdd(a + 0, v.x);
    atomicAdd(a + 1, v.y);
    atomicAdd(a + 2, v.z);
    atomicAdd(a + 3, v.w);
}

// ---------------------------------------------------------------------------
// Kernel 2: fp32 GEMM  out[n][j] = act( in[n][k] * W[k][j] + bias[j] )
// Pass 1: in = (1+eps)*x + agg (fused on load), act = relu.
// Pass 2: in = h (read from d_out), act = identity, written in-place to d_out
//         (safe: block stages its own 32 rows into LDS before the barrier).
// Tile: 32 nodes/block, 256 threads, each thread computes a 4x4 (node x col)
// register tile.  W (64 KB) + transposed input tile (16 KB) in LDS.
// Per k-step per thread: 2x b128 LDS reads + 16 v_fma_f32  -> VALU-bound.
// ---------------------------------------------------------------------------
__global__ __launch_bounds__(256, 2) void mlp_gemm(
    const float* in_a,                 // x (pass1) or h (pass2)
    const float* __restrict__ in_b,    // agg (pass1) or nullptr
    const float* __restrict__ epsp,
    const float* __restrict__ W,       // [k][j] row-major, 128x128
    const float* __restrict__ bias,
    float* out,
    int do_relu)
{
    __shared__ float Wl[D * D];                 // 64 KB
    __shared__ float inT[D * NODES_PER_BLOCK];  // 16 KB, layout [k][n]

    int tid = threadIdx.x;
    int node0 = blockIdx.x * NODES_PER_BLOCK;

    // Stage W: 16384 floats, 16 float4 per thread, coalesced.
    for (int i = tid; i < D * D / 4; i += 256)
        ((float4*)Wl)[i] = ((const float4*)W)[i];

    // Stage input tile transposed: [k][n].
    float ep = in_b ? (1.0f + epsp[0]) : 0.0f;
    for (int i = tid; i < NODES_PER_BLOCK * D / 4; i += 256) {
        int n  = i >> 5;    // 0..31  node within tile
        int k4 = i & 31;    // 0..31  float4 index along k
        const float4* pa = (const float4*)(in_a + (long long)(node0 + n) * D);
        float4 v = pa[k4];
        if (in_b) {
            const float4* pb = (const float4*)(in_b + (long long)(node0 + n) * D);
            float4 g = pb[k4];
            v.x = ep * v.x + g.x;  v.y = ep * v.y + g.y;
            v.z = ep * v.z + g.z;  v.w = ep * v.w + g.w;
        }
        int k = k4 * 4;
        inT[(k + 0) * NODES_PER_BLOCK + n] = v.x;
        inT[(k + 1) * NODES_PER_BLOCK + n] = v.y;
        inT[(k + 2) * NODES_PER_BLOCK + n] = v.z;
        inT[(k + 3) * NODES_PER_BLOCK + n] = v.w;
    }
    __syncthreads();

    int cg = tid & 31;    // col group: cols cg*4 .. cg*4+3
    int ng = tid >> 5;    // node group: nodes ng*4 .. ng*4+3

    float acc[4][4];
    #pragma unroll
    for (int n = 0; n < 4; ++n)
        #pragma unroll
        for (int c = 0; c < 4; ++c) acc[n][c] = 0.0f;

    #pragma unroll 4
    for (int k = 0; k < D; ++k) {
        float4 w = *(const float4*)&Wl[k * D + cg * 4];
        float4 a = *(const float4*)&inT[k * NODES_PER_BLOCK + ng * 4];
        acc[0][0] += a.x * w.x; acc[0][1] += a.x * w.y;
        acc[0][2] += a.x * w.z; acc[0][3] += a.x * w.w;
        acc[1][0] += a.y * w.x; acc[1][1] += a.y * w.y;
        acc[1][2] += a.y * w.z; acc[1][3] += a.y * w.w;
        acc[2][0] += a.z * w.x; acc[2][1] += a.z * w.y;
        acc[2][2] += a.z * w.z; acc[2][3] += a.z * w.w;
        acc[3][0] += a.w * w.x; acc[3][1] += a.w * w.y;
        acc[3][2] += a.w * w.z; acc[3][3] += a.w * w.w;
    }

    float4 b = ((const float4*)bias)[cg];
    #pragma unroll
    for (int n = 0; n < 4; ++n) {
        float4 r;
        r.x = acc[n][0] + b.x;  r.y = acc[n][1] + b.y;
        r.z = acc[n][2] + b.z;  r.w = acc[n][3] + b.w;
        if (do_relu) {
            r.x = fmaxf(r.x, 0.0f); r.y = fmaxf(r.y, 0.0f);
            r.z = fmaxf(r.z, 0.0f); r.w = fmaxf(r.w, 0.0f);
        }
        ((float4*)(out + (long long)(node0 + ng * 4 + n) * D))[cg] = r;
    }
}

extern "C" void kernel_launch(void* const* d_in, const int* in_sizes, int n_in,
                              void* d_out, int out_size, void* d_ws, size_t ws_size,
                              hipStream_t stream) {
    const float* x   = (const float*)d_in[0];
    const int*   ei  = (const int*)d_in[1];    // edge_index [2][E]
    const float* eps = (const float*)d_in[2];
    const float* W1  = (const float*)d_in[3];
    const float* b1  = (const float*)d_in[4];
    const float* W2  = (const float*)d_in[5];
    const float* b2  = (const float*)d_in[6];
    float* out = (float*)d_out;
    float* agg = (float*)d_ws;                 // N*D floats = 51.2 MB

    int E = in_sizes[1] / 2;                   // 1,600,000
    int N = in_sizes[0] / D;                   // 100,000

    // agg = 0  (d_ws is poisoned 0xAA before every timed launch)
    hipMemsetAsync(agg, 0, (size_t)N * D * sizeof(float), stream);

    // scatter: E edges * 32 threads each
    int sthreads_total = E * 32;
    int sblocks = (sthreads_total + 255) / 256;
    scatter_kernel<<<sblocks, 256, 0, stream>>>(x, ei, agg, E);

    // MLP layer 1: h = relu(((1+eps)x + agg) @ W1 + b1) -> d_out
    int gblocks = N / NODES_PER_BLOCK;         // 3125
    mlp_gemm<<<gblocks, 256, 0, stream>>>(x, agg, eps, W1, b1, out, 1);
    // MLP layer 2: y = h @ W2 + b2  (in-place on d_out)
    mlp_gemm<<<gblocks, 256, 0, stream>>>(out, nullptr, eps, W2, b2, out, 0);
}

// Round 2
// 755.092 us; speedup vs baseline: 3.9090x; 3.9090x over previous
//
#include <hip/hip_runtime.h>

#define D 128
#define NODES_PER_BLOCK 32
#define NN 100000   // nodes (checked against in_sizes at launch)

// ---------------------------------------------------------------------------
// CSR build step 1: degree histogram.  1.6M int atomics (vs 204.8M f32 before)
// ---------------------------------------------------------------------------
__global__ __launch_bounds__(256) void hist_kernel(
    const int* __restrict__ ei, int* __restrict__ deg, int E)
{
    int gid = blockIdx.x * 256 + threadIdx.x;
    if (gid >= E) return;
    atomicAdd(&deg[ei[E + gid]], 1);   // dst
}

// ---------------------------------------------------------------------------
// CSR build step 2: exclusive prefix scan of deg[N] -> rs[N].
// Single block, 1024 threads, each owns ceil(N/1024) consecutive elements.
// ---------------------------------------------------------------------------
__global__ __launch_bounds__(1024) void scan_kernel(
    const int* __restrict__ deg, int* __restrict__ rs, int N)
{
    __shared__ int psum[1024];
    int tid = threadIdx.x;
    int per = (N + 1023) / 1024;
    int base = tid * per;

    int s = 0;
    for (int i = 0; i < per; ++i) {
        int idx = base + i;
        if (idx < N) s += deg[idx];
    }
    psum[tid] = s;
    __syncthreads();

    // Hillis-Steele inclusive scan over the 1024 partials
    for (int off = 1; off < 1024; off <<= 1) {
        int t = (tid >= off) ? psum[tid - off] : 0;
        __syncthreads();
        psum[tid] += t;
        __syncthreads();
    }
    int run = psum[tid] - s;   // exclusive prefix of this thread's chunk
    for (int i = 0; i < per; ++i) {
        int idx = base + i;
        if (idx < N) { rs[idx] = run; run += deg[idx]; }
    }
}

// ---------------------------------------------------------------------------
// CSR build step 3: fill edge list.  pos = rs[dst]++ (atomic); csr[pos] = src.
// After this kernel rs[n] == inclusive prefix: node n's segment is
// [ n==0 ? 0 : rs[n-1],  rs[n] ).
// ---------------------------------------------------------------------------
__global__ __launch_bounds__(256) void fill_kernel(
    const int* __restrict__ ei, int* __restrict__ rs,
    int* __restrict__ csr, int E)
{
    int gid = blockIdx.x * 256 + threadIdx.x;
    if (gid >= E) return;
    int s = ei[gid];
    int d = ei[E + gid];
    int pos = atomicAdd(&rs[d], 1);
    csr[pos] = s;
}

// ---------------------------------------------------------------------------
// Gather: one wave (64 lanes) per node, lane owns float2 of the 128-float row.
// Per neighbor: one coalesced 512B load from x (L3-resident).  Writes each
// agg row exactly once (zero-degree nodes write zeros -> no memset needed).
// ---------------------------------------------------------------------------
__global__ __launch_bounds__(256) void gather_kernel(
    const float* __restrict__ x, const int* __restrict__ rs,
    const int* __restrict__ csr, float* __restrict__ agg, int N)
{
    int wave = threadIdx.x >> 6;
    int lane = threadIdx.x & 63;
    int node = blockIdx.x * 4 + wave;
    if (node >= N) return;

    int start = (node == 0) ? 0 : rs[node - 1];
    int end   = rs[node];

    float2 acc = make_float2(0.0f, 0.0f);
    int j = start;
    // unroll-by-2 for ILP (two independent loads in flight)
    for (; j + 1 < end; j += 2) {
        int s0 = csr[j], s1 = csr[j + 1];
        float2 v0 = ((const float2*)(x + (size_t)s0 * D))[lane];
        float2 v1 = ((const float2*)(x + (size_t)s1 * D))[lane];
        acc.x += v0.x + v1.x;
        acc.y += v0.y + v1.y;
    }
    if (j < end) {
        int s0 = csr[j];
        float2 v0 = ((const float2*)(x + (size_t)s0 * D))[lane];
        acc.x += v0.x;
        acc.y += v0.y;
    }
    ((float2*)(agg + (size_t)node * D))[lane] = acc;
}

// ---------------------------------------------------------------------------
// fp32 GEMM  out[n][j] = act( in[n][k] * W[k][j] + bias[j] )   (unchanged)
// ---------------------------------------------------------------------------
__global__ __launch_bounds__(256, 2) void mlp_gemm(
    const float* in_a, const float* __restrict__ in_b,
    const float* __restrict__ epsp, const float* __restrict__ W,
    const float* __restrict__ bias, float* out, int do_relu)
{
    __shared__ float Wl[D * D];                 // 64 KB
    __shared__ float inT[D * NODES_PER_BLOCK];  // 16 KB, layout [k][n]

    int tid = threadIdx.x;
    int node0 = blockIdx.x * NODES_PER_BLOCK;

    for (int i = tid; i < D * D / 4; i += 256)
        ((float4*)Wl)[i] = ((const float4*)W)[i];

    float ep = in_b ? (1.0f + epsp[0]) : 0.0f;
    for (int i = tid; i < NODES_PER_BLOCK * D / 4; i += 256) {
        int n  = i >> 5;
        int k4 = i & 31;
        const float4* pa = (const float4*)(in_a + (long long)(node0 + n) * D);
        float4 v = pa[k4];
        if (in_b) {
            const float4* pb = (const float4*)(in_b + (long long)(node0 + n) * D);
            float4 g = pb[k4];
            v.x = ep * v.x + g.x;  v.y = ep * v.y + g.y;
            v.z = ep * v.z + g.z;  v.w = ep * v.w + g.w;
        }
        int k = k4 * 4;
        inT[(k + 0) * NODES_PER_BLOCK + n] = v.x;
        inT[(k + 1) * NODES_PER_BLOCK + n] = v.y;
        inT[(k + 2) * NODES_PER_BLOCK + n] = v.z;
        inT[(k + 3) * NODES_PER_BLOCK + n] = v.w;
    }
    __syncthreads();

    int cg = tid & 31;
    int ng = tid >> 5;

    float acc[4][4];
    #pragma unroll
    for (int n = 0; n < 4; ++n)
        #pragma unroll
        for (int c = 0; c < 4; ++c) acc[n][c] = 0.0f;

    #pragma unroll 4
    for (int k = 0; k < D; ++k) {
        float4 w = *(const float4*)&Wl[k * D + cg * 4];
        float4 a = *(const float4*)&inT[k * NODES_PER_BLOCK + ng * 4];
        acc[0][0] += a.x * w.x; acc[0][1] += a.x * w.y;
        acc[0][2] += a.x * w.z; acc[0][3] += a.x * w.w;
        acc[1][0] += a.y * w.x; acc[1][1] += a.y * w.y;
        acc[1][2] += a.y * w.z; acc[1][3] += a.y * w.w;
        acc[2][0] += a.z * w.x; acc[2][1] += a.z * w.y;
        acc[2][2] += a.z * w.z; acc[2][3] += a.z * w.w;
        acc[3][0] += a.w * w.x; acc[3][1] += a.w * w.y;
        acc[3][2] += a.w * w.z; acc[3][3] += a.w * w.w;
    }

    float4 b = ((const float4*)bias)[cg];
    #pragma unroll
    for (int n = 0; n < 4; ++n) {
        float4 r;
        r.x = acc[n][0] + b.x;  r.y = acc[n][1] + b.y;
        r.z = acc[n][2] + b.z;  r.w = acc[n][3] + b.w;
        if (do_relu) {
            r.x = fmaxf(r.x, 0.0f); r.y = fmaxf(r.y, 0.0f);
            r.z = fmaxf(r.z, 0.0f); r.w = fmaxf(r.w, 0.0f);
        }
        ((float4*)(out + (long long)(node0 + ng * 4 + n) * D))[cg] = r;
    }
}

extern "C" void kernel_launch(void* const* d_in, const int* in_sizes, int n_in,
                              void* d_out, int out_size, void* d_ws, size_t ws_size,
                              hipStream_t stream) {
    const float* x   = (const float*)d_in[0];
    const int*   ei  = (const int*)d_in[1];    // edge_index [2][E]
    const float* eps = (const float*)d_in[2];
    const float* W1  = (const float*)d_in[3];
    const float* b1  = (const float*)d_in[4];
    const float* W2  = (const float*)d_in[5];
    const float* b2  = (const float*)d_in[6];
    float* out = (float*)d_out;

    int E = in_sizes[1] / 2;                   // 1,600,000
    int N = in_sizes[0] / D;                   // 100,000

    // workspace layout (bytes, all 16B-aligned):
    //   [0, 400000)            deg   int[N]
    //   [400000, 800000)       rs    int[N]
    //   [800000, 7200000)      csr   int[E]
    //   [7200000, +N*D*4)      agg   float[N*D]
    char* ws = (char*)d_ws;
    int* deg   = (int*)(ws);
    int* rs    = (int*)(ws + 400000);
    int* csr   = (int*)(ws + 800000);
    float* agg = (float*)(ws + 7200000);

    hipMemsetAsync(deg, 0, (size_t)N * sizeof(int), stream);

    int eblocks = (E + 255) / 256;             // 6250
    hist_kernel<<<eblocks, 256, 0, stream>>>(ei, deg, E);
    scan_kernel<<<1, 1024, 0, stream>>>(deg, rs, N);
    fill_kernel<<<eblocks, 256, 0, stream>>>(ei, rs, csr, E);

    int gblocks_gather = (N + 3) / 4;          // 25000 (4 waves/block, 1 node/wave)
    gather_kernel<<<gblocks_gather, 256, 0, stream>>>(x, rs, csr, agg, N);

    int gblocks = N / NODES_PER_BLOCK;         // 3125
    mlp_gemm<<<gblocks, 256, 0, stream>>>(x, agg, eps, W1, b1, out, 1);
    mlp_gemm<<<gblocks, 256, 0, stream>>>(out, nullptr, eps, W2, b2, out, 0);
}

// Round 3
// 563.764 us; speedup vs baseline: 5.2356x; 1.3394x over previous
//
#include <hip/hip_runtime.h>

#define D 128
#define NODES_PER_BLOCK 32
#define SCAN_CHUNK 1024   // elements per scan block (256 threads x int4)

// ---------------------------------------------------------------------------
// CSR build step 1: degree histogram.
// ---------------------------------------------------------------------------
__global__ __launch_bounds__(256) void hist_kernel(
    const int* __restrict__ ei, int* __restrict__ deg, int E)
{
    int gid = blockIdx.x * 256 + threadIdx.x;
    if (gid >= E) return;
    atomicAdd(&deg[ei[E + gid]], 1);   // dst
}

// ---------------------------------------------------------------------------
// Scan phase A: per-block sums of deg (coalesced int4 loads).
// ---------------------------------------------------------------------------
__global__ __launch_bounds__(256) void scan_blocksums(
    const int* __restrict__ deg, int* __restrict__ part, int N)
{
    int tid = threadIdx.x;
    int idx = blockIdx.x * SCAN_CHUNK + tid * 4;
    int s = 0;
    if (idx < N) {                       // N % 4 == 0 -> full int4 in bounds
        int4 v = *(const int4*)(deg + idx);
        s = v.x + v.y + v.z + v.w;
    }
    #pragma unroll
    for (int off = 32; off > 0; off >>= 1) s += __shfl_down(s, off);
    __shared__ int ws[4];
    int wave = tid >> 6, lane = tid & 63;
    if (lane == 0) ws[wave] = s;
    __syncthreads();
    if (tid == 0) part[blockIdx.x] = ws[0] + ws[1] + ws[2] + ws[3];
}

// ---------------------------------------------------------------------------
// Scan phase B: one wave scans the NB partials in-place (-> exclusive).
// ---------------------------------------------------------------------------
__global__ __launch_bounds__(64) void scan_partials(int* part, int NB)
{
    int lane = threadIdx.x;
    int carry = 0;
    for (int base = 0; base < NB; base += 64) {
        int i = base + lane;
        int v = (i < NB) ? part[i] : 0;
        int sc = v;
        #pragma unroll
        for (int off = 1; off < 64; off <<= 1) {
            int t = __shfl_up(sc, off);
            if (lane >= off) sc += t;
        }
        if (i < NB) part[i] = carry + sc - v;   // exclusive prefix
        carry += __shfl(sc, 63);                // block total
    }
}

// ---------------------------------------------------------------------------
// Scan phase C: re-read deg, block-level exclusive scan + block offset -> rs.
// ---------------------------------------------------------------------------
__global__ __launch_bounds__(256) void scan_final(
    const int* __restrict__ deg, const int* __restrict__ part,
    int* __restrict__ rs, int N)
{
    int tid = threadIdx.x;
    int idx = blockIdx.x * SCAN_CHUNK + tid * 4;
    int4 v = make_int4(0, 0, 0, 0);
    if (idx < N) v = *(const int4*)(deg + idx);
    int s = v.x + v.y + v.z + v.w;

    int lane = tid & 63, wave = tid >> 6;
    int sc = s;
    #pragma unroll
    for (int off = 1; off < 64; off <<= 1) {
        int t = __shfl_up(sc, off);
        if (lane >= off) sc += t;
    }
    __shared__ int ws[4];
    if (lane == 63) ws[wave] = sc;
    __syncthreads();
    int woff = 0;
    #pragma unroll
    for (int w = 0; w < 4; ++w) if (w < wave) woff += ws[w];

    if (idx < N) {
        int ex = part[blockIdx.x] + woff + (sc - s);
        int4 o;
        o.x = ex;
        o.y = o.x + v.x;
        o.z = o.y + v.y;
        o.w = o.z + v.z;
        *(int4*)(rs + idx) = o;
    }
}

// ---------------------------------------------------------------------------
// CSR build step 3: fill edge list.  pos = rs[dst]++ (atomic); csr[pos] = src.
// After this kernel rs[n] == inclusive prefix.
// ---------------------------------------------------------------------------
__global__ __launch_bounds__(256) void fill_kernel(
    const int* __restrict__ ei, int* __restrict__ rs,
    int* __restrict__ csr, int E)
{
    int gid = blockIdx.x * 256 + threadIdx.x;
    if (gid >= E) return;
    int s = ei[gid];
    int d = ei[E + gid];
    int pos = atomicAdd(&rs[d], 1);
    csr[pos] = s;
}

// ---------------------------------------------------------------------------
// Gather: one wave per node, lane owns float2 of the 128-float row.
// ---------------------------------------------------------------------------
__global__ __launch_bounds__(256) void gather_kernel(
    const float* __restrict__ x, const int* __restrict__ rs,
    const int* __restrict__ csr, float* __restrict__ agg, int N)
{
    int wave = threadIdx.x >> 6;
    int lane = threadIdx.x & 63;
    int node = blockIdx.x * 4 + wave;
    if (node >= N) return;

    int start = (node == 0) ? 0 : rs[node - 1];
    int end   = rs[node];

    float2 acc = make_float2(0.0f, 0.0f);
    int j = start;
    for (; j + 1 < end; j += 2) {
        int s0 = csr[j], s1 = csr[j + 1];
        float2 v0 = ((const float2*)(x + (size_t)s0 * D))[lane];
        float2 v1 = ((const float2*)(x + (size_t)s1 * D))[lane];
        acc.x += v0.x + v1.x;
        acc.y += v0.y + v1.y;
    }
    if (j < end) {
        int s0 = csr[j];
        float2 v0 = ((const float2*)(x + (size_t)s0 * D))[lane];
        acc.x += v0.x;
        acc.y += v0.y;
    }
    ((float2*)(agg + (size_t)node * D))[lane] = acc;
}

// ---------------------------------------------------------------------------
// fp32 GEMM  out[n][j] = act( in[n][k] * W[k][j] + bias[j] )   (unchanged)
// ---------------------------------------------------------------------------
__global__ __launch_bounds__(256, 2) void mlp_gemm(
    const float* in_a, const float* __restrict__ in_b,
    const float* __restrict__ epsp, const float* __restrict__ W,
    const float* __restrict__ bias, float* out, int do_relu)
{
    __shared__ float Wl[D * D];                 // 64 KB
    __shared__ float inT[D * NODES_PER_BLOCK];  // 16 KB, layout [k][n]

    int tid = threadIdx.x;
    int node0 = blockIdx.x * NODES_PER_BLOCK;

    for (int i = tid; i < D * D / 4; i += 256)
        ((float4*)Wl)[i] = ((const float4*)W)[i];

    float ep = in_b ? (1.0f + epsp[0]) : 0.0f;
    for (int i = tid; i < NODES_PER_BLOCK * D / 4; i += 256) {
        int n  = i >> 5;
        int k4 = i & 31;
        const float4* pa = (const float4*)(in_a + (long long)(node0 + n) * D);
        float4 v = pa[k4];
        if (in_b) {
            const float4* pb = (const float4*)(in_b + (long long)(node0 + n) * D);
            float4 g = pb[k4];
            v.x = ep * v.x + g.x;  v.y = ep * v.y + g.y;
            v.z = ep * v.z + g.z;  v.w = ep * v.w + g.w;
        }
        int k = k4 * 4;
        inT[(k + 0) * NODES_PER_BLOCK + n] = v.x;
        inT[(k + 1) * NODES_PER_BLOCK + n] = v.y;
        inT[(k + 2) * NODES_PER_BLOCK + n] = v.z;
        inT[(k + 3) * NODES_PER_BLOCK + n] = v.w;
    }
    __syncthreads();

    int cg = tid & 31;
    int ng = tid >> 5;

    float acc[4][4];
    #pragma unroll
    for (int n = 0; n < 4; ++n)
        #pragma unroll
        for (int c = 0; c < 4; ++c) acc[n][c] = 0.0f;

    #pragma unroll 4
    for (int k = 0; k < D; ++k) {
        float4 w = *(const float4*)&Wl[k * D + cg * 4];
        float4 a = *(const float4*)&inT[k * NODES_PER_BLOCK + ng * 4];
        acc[0][0] += a.x * w.x; acc[0][1] += a.x * w.y;
        acc[0][2] += a.x * w.z; acc[0][3] += a.x * w.w;
        acc[1][0] += a.y * w.x; acc[1][1] += a.y * w.y;
        acc[1][2] += a.y * w.z; acc[1][3] += a.y * w.w;
        acc[2][0] += a.z * w.x; acc[2][1] += a.z * w.y;
        acc[2][2] += a.z * w.z; acc[2][3] += a.z * w.w;
        acc[3][0] += a.w * w.x; acc[3][1] += a.w * w.y;
        acc[3][2] += a.w * w.z; acc[3][3] += a.w * w.w;
    }

    float4 b = ((const float4*)bias)[cg];
    #pragma unroll
    for (int n = 0; n < 4; ++n) {
        float4 r;
        r.x = acc[n][0] + b.x;  r.y = acc[n][1] + b.y;
        r.z = acc[n][2] + b.z;  r.w = acc[n][3] + b.w;
        if (do_relu) {
            r.x = fmaxf(r.x, 0.0f); r.y = fmaxf(r.y, 0.0f);
            r.z = fmaxf(r.z, 0.0f); r.w = fmaxf(r.w, 0.0f);
        }
        ((float4*)(out + (long long)(node0 + ng * 4 + n) * D))[cg] = r;
    }
}

extern "C" void kernel_launch(void* const* d_in, const int* in_sizes, int n_in,
                              void* d_out, int out_size, void* d_ws, size_t ws_size,
                              hipStream_t stream) {
    const float* x   = (const float*)d_in[0];
    const int*   ei  = (const int*)d_in[1];    // edge_index [2][E]
    const float* eps = (const float*)d_in[2];
    const float* W1  = (const float*)d_in[3];
    const float* b1  = (const float*)d_in[4];
    const float* W2  = (const float*)d_in[5];
    const float* b2  = (const float*)d_in[6];
    float* out = (float*)d_out;

    int E = in_sizes[1] / 2;                   // 1,600,000
    int N = in_sizes[0] / D;                   // 100,000

    // workspace layout (bytes, all 16B-aligned):
    //   [0, 400000)            deg   int[N]
    //   [400000, 800000)       rs    int[N]
    //   [800000, 801024)       part  int[NB]   (scan partials, NB<=256)
    //   [801024, 7201024)      csr   int[E]
    //   [7201024, +N*D*4)      agg   float[N*D]
    char* ws = (char*)d_ws;
    int* deg   = (int*)(ws);
    int* rs    = (int*)(ws + 400000);
    int* part  = (int*)(ws + 800000);
    int* csr   = (int*)(ws + 801024);
    float* agg = (float*)(ws + 7201024);

    hipMemsetAsync(deg, 0, (size_t)N * sizeof(int), stream);

    int eblocks = (E + 255) / 256;             // 6250
    hist_kernel<<<eblocks, 256, 0, stream>>>(ei, deg, E);

    int NB = (N + SCAN_CHUNK - 1) / SCAN_CHUNK;  // 98
    scan_blocksums<<<NB, 256, 0, stream>>>(deg, part, N);
    scan_partials<<<1, 64, 0, stream>>>(part, NB);
    scan_final<<<NB, 256, 0, stream>>>(deg, part, rs, N);

    fill_kernel<<<eblocks, 256, 0, stream>>>(ei, rs, csr, E);

    int gblocks_gather = (N + 3) / 4;          // 25000
    gather_kernel<<<gblocks_gather, 256, 0, stream>>>(x, rs, csr, agg, N);

    int gblocks = N / NODES_PER_BLOCK;         // 3125
    mlp_gemm<<<gblocks, 256, 0, stream>>>(x, agg, eps, W1, b1, out, 1);
    mlp_gemm<<<gblocks, 256, 0, stream>>>(out, nullptr, eps, W2, b2, out, 0);
}

// Round 4
// 517.672 us; speedup vs baseline: 5.7017x; 1.0890x over previous
//
#include <hip/hip_runtime.h>

#define D 128
#define NODES_PER_BLOCK 32
#define SCAN_CHUNK 1024   // elements per scan block (256 threads x int4)
#define NSLICE 8          // XCD count: blockIdx%8 -> XCD (perf heuristic)

// ---------------------------------------------------------------------------
// CSR step 1: degree histogram, XCD-sliced.  Block b only processes dsts in
// slice (b&7) so each XCD's atomic working set (~50 KB of deg) stays in its
// own L2.  Costs an 8x re-read of the dst array (L3-resident, cheap).
// ---------------------------------------------------------------------------
__global__ __launch_bounds__(256) void hist_kernel(
    const int* __restrict__ ei, int* __restrict__ deg, int E, int sliceSize)
{
    int slice = blockIdx.x & (NSLICE - 1);
    int gid = (blockIdx.x >> 3) * 256 + threadIdx.x;
    if (gid >= E) return;
    int d = ei[E + gid];
    int lo = slice * sliceSize;
    if (d < lo || d >= lo + sliceSize) return;
    atomicAdd(&deg[d], 1);
}

// ---------------------------------------------------------------------------
// Scan phase A: per-block sums of deg (coalesced int4 loads).
// ---------------------------------------------------------------------------
__global__ __launch_bounds__(256) void scan_blocksums(
    const int* __restrict__ deg, int* __restrict__ part, int N)
{
    int tid = threadIdx.x;
    int idx = blockIdx.x * SCAN_CHUNK + tid * 4;
    int s = 0;
    if (idx < N) {
        int4 v = *(const int4*)(deg + idx);
        s = v.x + v.y + v.z + v.w;
    }
    #pragma unroll
    for (int off = 32; off > 0; off >>= 1) s += __shfl_down(s, off);
    __shared__ int ws[4];
    int wave = tid >> 6, lane = tid & 63;
    if (lane == 0) ws[wave] = s;
    __syncthreads();
    if (tid == 0) part[blockIdx.x] = ws[0] + ws[1] + ws[2] + ws[3];
}

// ---------------------------------------------------------------------------
// Scan phase B: one wave scans the NB partials in-place (-> exclusive).
// ---------------------------------------------------------------------------
__global__ __launch_bounds__(64) void scan_partials(int* part, int NB)
{
    int lane = threadIdx.x;
    int carry = 0;
    for (int base = 0; base < NB; base += 64) {
        int i = base + lane;
        int v = (i < NB) ? part[i] : 0;
        int sc = v;
        #pragma unroll
        for (int off = 1; off < 64; off <<= 1) {
            int t = __shfl_up(sc, off);
            if (lane >= off) sc += t;
        }
        if (i < NB) part[i] = carry + sc - v;
        carry += __shfl(sc, 63);
    }
}

// ---------------------------------------------------------------------------
// Scan phase C: re-read deg, block-level exclusive scan + block offset -> rs.
// ---------------------------------------------------------------------------
__global__ __launch_bounds__(256) void scan_final(
    const int* __restrict__ deg, const int* __restrict__ part,
    int* __restrict__ rs, int N)
{
    int tid = threadIdx.x;
    int idx = blockIdx.x * SCAN_CHUNK + tid * 4;
    int4 v = make_int4(0, 0, 0, 0);
    if (idx < N) v = *(const int4*)(deg + idx);
    int s = v.x + v.y + v.z + v.w;

    int lane = tid & 63, wave = tid >> 6;
    int sc = s;
    #pragma unroll
    for (int off = 1; off < 64; off <<= 1) {
        int t = __shfl_up(sc, off);
        if (lane >= off) sc += t;
    }
    __shared__ int ws[4];
    if (lane == 63) ws[wave] = sc;
    __syncthreads();
    int woff = 0;
    #pragma unroll
    for (int w = 0; w < 4; ++w) if (w < wave) woff += ws[w];

    if (idx < N) {
        int ex = part[blockIdx.x] + woff + (sc - s);
        int4 o;
        o.x = ex;
        o.y = o.x + v.x;
        o.z = o.y + v.y;
        o.w = o.z + v.z;
        *(int4*)(rs + idx) = o;
    }
}

// ---------------------------------------------------------------------------
// CSR step 3: fill, XCD-sliced like hist.  Slice b&7 writes only its ~800 KB
// contiguous csr region -> stays in that XCD's L2 -> full-line writebacks
// (was: 106 MB of partial-line HBM writes for a 6.4 MB array).
// After this kernel rs[n] == inclusive prefix.
// ---------------------------------------------------------------------------
__global__ __launch_bounds__(256) void fill_kernel(
    const int* __restrict__ ei, int* __restrict__ rs,
    int* __restrict__ csr, int E, int sliceSize)
{
    int slice = blockIdx.x & (NSLICE - 1);
    int gid = (blockIdx.x >> 3) * 256 + threadIdx.x;
    if (gid >= E) return;
    int d = ei[E + gid];
    int lo = slice * sliceSize;
    if (d < lo || d >= lo + sliceSize) return;
    int s = ei[gid];
    int pos = atomicAdd(&rs[d], 1);
    csr[pos] = s;
}

// ---------------------------------------------------------------------------
// Gather: 32 lanes per node (float4/lane), 2 nodes per wave, unroll-4 ->
// 4 KB of row loads in flight per wave (was 1 KB) for latency hiding.
// Writes each agg row exactly once; zero-degree rows get zeros.
// ---------------------------------------------------------------------------
__global__ __launch_bounds__(256) void gather_kernel(
    const float* __restrict__ x, const int* __restrict__ rs,
    const int* __restrict__ csr, float* __restrict__ agg, int N)
{
    int sub  = threadIdx.x >> 5;        // 0..7: which node-slot in block
    int lane = threadIdx.x & 31;        // float4 index within row
    int node = blockIdx.x * 8 + sub;
    if (node >= N) return;

    int start = (node == 0) ? 0 : rs[node - 1];
    int end   = rs[node];

    float4 acc = make_float4(0.f, 0.f, 0.f, 0.f);
    int j = start;
    for (; j + 3 < end; j += 4) {
        int s0 = csr[j], s1 = csr[j + 1], s2 = csr[j + 2], s3 = csr[j + 3];
        float4 v0 = ((const float4*)(x + (size_t)s0 * D))[lane];
        float4 v1 = ((const float4*)(x + (size_t)s1 * D))[lane];
        float4 v2 = ((const float4*)(x + (size_t)s2 * D))[lane];
        float4 v3 = ((const float4*)(x + (size_t)s3 * D))[lane];
        acc.x += (v0.x + v1.x) + (v2.x + v3.x);
        acc.y += (v0.y + v1.y) + (v2.y + v3.y);
        acc.z += (v0.z + v1.z) + (v2.z + v3.z);
        acc.w += (v0.w + v1.w) + (v2.w + v3.w);
    }
    for (; j < end; ++j) {
        int s0 = csr[j];
        float4 v0 = ((const float4*)(x + (size_t)s0 * D))[lane];
        acc.x += v0.x; acc.y += v0.y; acc.z += v0.z; acc.w += v0.w;
    }
    ((float4*)(agg + (size_t)node * D))[lane] = acc;
}

// ---------------------------------------------------------------------------
// fp32 GEMM  out[n][j] = act( in[n][k] * W[k][j] + bias[j] )   (unchanged)
// ---------------------------------------------------------------------------
__global__ __launch_bounds__(256, 2) void mlp_gemm(
    const float* in_a, const float* __restrict__ in_b,
    const float* __restrict__ epsp, const float* __restrict__ W,
    const float* __restrict__ bias, float* out, int do_relu)
{
    __shared__ float Wl[D * D];                 // 64 KB
    __shared__ float inT[D * NODES_PER_BLOCK];  // 16 KB, layout [k][n]

    int tid = threadIdx.x;
    int node0 = blockIdx.x * NODES_PER_BLOCK;

    for (int i = tid; i < D * D / 4; i += 256)
        ((float4*)Wl)[i] = ((const float4*)W)[i];

    float ep = in_b ? (1.0f + epsp[0]) : 0.0f;
    for (int i = tid; i < NODES_PER_BLOCK * D / 4; i += 256) {
        int n  = i >> 5;
        int k4 = i & 31;
        const float4* pa = (const float4*)(in_a + (long long)(node0 + n) * D);
        float4 v = pa[k4];
        if (in_b) {
            const float4* pb = (const float4*)(in_b + (long long)(node0 + n) * D);
            float4 g = pb[k4];
            v.x = ep * v.x + g.x;  v.y = ep * v.y + g.y;
            v.z = ep * v.z + g.z;  v.w = ep * v.w + g.w;
        }
        int k = k4 * 4;
        inT[(k + 0) * NODES_PER_BLOCK + n] = v.x;
        inT[(k + 1) * NODES_PER_BLOCK + n] = v.y;
        inT[(k + 2) * NODES_PER_BLOCK + n] = v.z;
        inT[(k + 3) * NODES_PER_BLOCK + n] = v.w;
    }
    __syncthreads();

    int cg = tid & 31;
    int ng = tid >> 5;

    float acc[4][4];
    #pragma unroll
    for (int n = 0; n < 4; ++n)
        #pragma unroll
        for (int c = 0; c < 4; ++c) acc[n][c] = 0.0f;

    #pragma unroll 4
    for (int k = 0; k < D; ++k) {
        float4 w = *(const float4*)&Wl[k * D + cg * 4];
        float4 a = *(const float4*)&inT[k * NODES_PER_BLOCK + ng * 4];
        acc[0][0] += a.x * w.x; acc[0][1] += a.x * w.y;
        acc[0][2] += a.x * w.z; acc[0][3] += a.x * w.w;
        acc[1][0] += a.y * w.x; acc[1][1] += a.y * w.y;
        acc[1][2] += a.y * w.z; acc[1][3] += a.y * w.w;
        acc[2][0] += a.z * w.x; acc[2][1] += a.z * w.y;
        acc[2][2] += a.z * w.z; acc[2][3] += a.z * w.w;
        acc[3][0] += a.w * w.x; acc[3][1] += a.w * w.y;
        acc[3][2] += a.w * w.z; acc[3][3] += a.w * w.w;
    }

    float4 b = ((const float4*)bias)[cg];
    #pragma unroll
    for (int n = 0; n < 4; ++n) {
        float4 r;
        r.x = acc[n][0] + b.x;  r.y = acc[n][1] + b.y;
        r.z = acc[n][2] + b.z;  r.w = acc[n][3] + b.w;
        if (do_relu) {
            r.x = fmaxf(r.x, 0.0f); r.y = fmaxf(r.y, 0.0f);
            r.z = fmaxf(r.z, 0.0f); r.w = fmaxf(r.w, 0.0f);
        }
        ((float4*)(out + (long long)(node0 + ng * 4 + n) * D))[cg] = r;
    }
}

extern "C" void kernel_launch(void* const* d_in, const int* in_sizes, int n_in,
                              void* d_out, int out_size, void* d_ws, size_t ws_size,
                              hipStream_t stream) {
    const float* x   = (const float*)d_in[0];
    const int*   ei  = (const int*)d_in[1];    // edge_index [2][E]
    const float* eps = (const float*)d_in[2];
    const float* W1  = (const float*)d_in[3];
    const float* b1  = (const float*)d_in[4];
    const float* W2  = (const float*)d_in[5];
    const float* b2  = (const float*)d_in[6];
    float* out = (float*)d_out;

    int E = in_sizes[1] / 2;                   // 1,600,000
    int N = in_sizes[0] / D;                   // 100,000
    int sliceSize = (N + NSLICE - 1) / NSLICE; // 12,500

    // workspace layout (bytes, all 16B-aligned):
    //   [0, 400000)            deg   int[N]
    //   [400000, 800000)       rs    int[N]
    //   [800000, 801024)       part  int[NB]
    //   [801024, 7201024)      csr   int[E]
    //   [7201024, +N*D*4)      agg   float[N*D]
    char* ws = (char*)d_ws;
    int* deg   = (int*)(ws);
    int* rs    = (int*)(ws + 400000);
    int* part  = (int*)(ws + 800000);
    int* csr   = (int*)(ws + 801024);
    float* agg = (float*)(ws + 7201024);

    hipMemsetAsync(deg, 0, (size_t)N * sizeof(int), stream);

    int eblocks = (E + 255) / 256;             // 6250
    hist_kernel<<<eblocks * NSLICE, 256, 0, stream>>>(ei, deg, E, sliceSize);

    int NB = (N + SCAN_CHUNK - 1) / SCAN_CHUNK;  // 98
    scan_blocksums<<<NB, 256, 0, stream>>>(deg, part, N);
    scan_partials<<<1, 64, 0, stream>>>(part, NB);
    scan_final<<<NB, 256, 0, stream>>>(deg, part, rs, N);

    fill_kernel<<<eblocks * NSLICE, 256, 0, stream>>>(ei, rs, csr, E, sliceSize);

    int gblocks_gather = (N + 7) / 8;          // 12500 (8 nodes/block)
    gather_kernel<<<gblocks_gather, 256, 0, stream>>>(x, rs, csr, agg, N);

    int gblocks = N / NODES_PER_BLOCK;         // 3125
    mlp_gemm<<<gblocks, 256, 0, stream>>>(x, agg, eps, W1, b1, out, 1);
    mlp_gemm<<<gblocks, 256, 0, stream>>>(out, nullptr, eps, W2, b2, out, 0);
}

// Round 5
// 482.180 us; speedup vs baseline: 6.1214x; 1.0736x over previous
//
#include <hip/hip_runtime.h>

#define D 128
#define NODES_PER_BLOCK 32
#define SCAN_CHUNK 1024   // elements per scan block (256 threads x int4)
#define NSLICE 8          // XCD count: blockIdx%8 -> XCD (perf heuristic)

// ---------------------------------------------------------------------------
// Convert x (fp32) -> xb (bf16 stored as ushort), RNE.  Halves gather bytes.
// ---------------------------------------------------------------------------
__global__ __launch_bounds__(256) void convert_kernel(
    const float* __restrict__ x, unsigned short* __restrict__ xb, int total4)
{
    int gid = blockIdx.x * 256 + threadIdx.x;
    if (gid >= total4) return;
    float4 v = ((const float4*)x)[gid];
    union { float f; unsigned int u; } c;
    ushort4 o;
    c.f = v.x; o.x = (unsigned short)((c.u + 0x7FFFu + ((c.u >> 16) & 1u)) >> 16);
    c.f = v.y; o.y = (unsigned short)((c.u + 0x7FFFu + ((c.u >> 16) & 1u)) >> 16);
    c.f = v.z; o.z = (unsigned short)((c.u + 0x7FFFu + ((c.u >> 16) & 1u)) >> 16);
    c.f = v.w; o.w = (unsigned short)((c.u + 0x7FFFu + ((c.u >> 16) & 1u)) >> 16);
    ((ushort4*)xb)[gid] = o;
}

// ---------------------------------------------------------------------------
// CSR step 1: degree histogram, XCD-sliced (see round-4 notes).
// ---------------------------------------------------------------------------
__global__ __launch_bounds__(256) void hist_kernel(
    const int* __restrict__ ei, int* __restrict__ deg, int E, int sliceSize)
{
    int slice = blockIdx.x & (NSLICE - 1);
    int gid = (blockIdx.x >> 3) * 256 + threadIdx.x;
    if (gid >= E) return;
    int d = ei[E + gid];
    int lo = slice * sliceSize;
    if (d < lo || d >= lo + sliceSize) return;
    atomicAdd(&deg[d], 1);
}

// ---------------------------------------------------------------------------
// Scan phase A: per-block sums of deg (coalesced int4 loads).
// ---------------------------------------------------------------------------
__global__ __launch_bounds__(256) void scan_blocksums(
    const int* __restrict__ deg, int* __restrict__ part, int N)
{
    int tid = threadIdx.x;
    int idx = blockIdx.x * SCAN_CHUNK + tid * 4;
    int s = 0;
    if (idx < N) {
        int4 v = *(const int4*)(deg + idx);
        s = v.x + v.y + v.z + v.w;
    }
    #pragma unroll
    for (int off = 32; off > 0; off >>= 1) s += __shfl_down(s, off);
    __shared__ int ws[4];
    int wave = tid >> 6, lane = tid & 63;
    if (lane == 0) ws[wave] = s;
    __syncthreads();
    if (tid == 0) part[blockIdx.x] = ws[0] + ws[1] + ws[2] + ws[3];
}

// ---------------------------------------------------------------------------
// Scan phase B: one wave scans the NB partials in-place (-> exclusive).
// ---------------------------------------------------------------------------
__global__ __launch_bounds__(64) void scan_partials(int* part, int NB)
{
    int lane = threadIdx.x;
    int carry = 0;
    for (int base = 0; base < NB; base += 64) {
        int i = base + lane;
        int v = (i < NB) ? part[i] : 0;
        int sc = v;
        #pragma unroll
        for (int off = 1; off < 64; off <<= 1) {
            int t = __shfl_up(sc, off);
            if (lane >= off) sc += t;
        }
        if (i < NB) part[i] = carry + sc - v;
        carry += __shfl(sc, 63);
    }
}

// ---------------------------------------------------------------------------
// Scan phase C: re-read deg, block-level exclusive scan + block offset -> rs.
// ---------------------------------------------------------------------------
__global__ __launch_bounds__(256) void scan_final(
    const int* __restrict__ deg, const int* __restrict__ part,
    int* __restrict__ rs, int N)
{
    int tid = threadIdx.x;
    int idx = blockIdx.x * SCAN_CHUNK + tid * 4;
    int4 v = make_int4(0, 0, 0, 0);
    if (idx < N) v = *(const int4*)(deg + idx);
    int s = v.x + v.y + v.z + v.w;

    int lane = tid & 63, wave = tid >> 6;
    int sc = s;
    #pragma unroll
    for (int off = 1; off < 64; off <<= 1) {
        int t = __shfl_up(sc, off);
        if (lane >= off) sc += t;
    }
    __shared__ int ws[4];
    if (lane == 63) ws[wave] = sc;
    __syncthreads();
    int woff = 0;
    #pragma unroll
    for (int w = 0; w < 4; ++w) if (w < wave) woff += ws[w];

    if (idx < N) {
        int ex = part[blockIdx.x] + woff + (sc - s);
        int4 o;
        o.x = ex;
        o.y = o.x + v.x;
        o.z = o.y + v.y;
        o.w = o.z + v.z;
        *(int4*)(rs + idx) = o;
    }
}

// ---------------------------------------------------------------------------
// CSR step 3: fill, XCD-sliced.  After this kernel rs[n] == inclusive prefix.
// ---------------------------------------------------------------------------
__global__ __launch_bounds__(256) void fill_kernel(
    const int* __restrict__ ei, int* __restrict__ rs,
    int* __restrict__ csr, int E, int sliceSize)
{
    int slice = blockIdx.x & (NSLICE - 1);
    int gid = (blockIdx.x >> 3) * 256 + threadIdx.x;
    if (gid >= E) return;
    int d = ei[E + gid];
    int lo = slice * sliceSize;
    if (d < lo || d >= lo + sliceSize) return;
    int s = ei[gid];
    int pos = atomicAdd(&rs[d], 1);
    csr[pos] = s;
}

// ---------------------------------------------------------------------------
// Gather (bf16 source): 32 lanes per node, ushort4 (4 bf16) per lane,
// fp32 accumulate, unroll-4.  Row read = 256 B (was 512 B) -> halves the
// L2-miss-path bytes that bound this kernel.  agg written fp32, once per row.
// ---------------------------------------------------------------------------
__global__ __launch_bounds__(256) void gather_kernel(
    const unsigned short* __restrict__ xb, const int* __restrict__ rs,
    const int* __restrict__ csr, float* __restrict__ agg, int N)
{
    int sub  = threadIdx.x >> 5;        // 0..7: node slot in block
    int lane = threadIdx.x & 31;        // ushort4 index within row
    int node = blockIdx.x * 8 + sub;
    if (node >= N) return;

    int start = (node == 0) ? 0 : rs[node - 1];
    int end   = rs[node];

    float4 acc = make_float4(0.f, 0.f, 0.f, 0.f);
    union { unsigned int u; float f; } c;
    #define BF2F(us) (c.u = ((unsigned int)(us)) << 16, c.f)

    int j = start;
    for (; j + 3 < end; j += 4) {
        int s0 = csr[j], s1 = csr[j + 1], s2 = csr[j + 2], s3 = csr[j + 3];
        ushort4 v0 = ((const ushort4*)(xb + (size_t)s0 * D))[lane];
        ushort4 v1 = ((const ushort4*)(xb + (size_t)s1 * D))[lane];
        ushort4 v2 = ((const ushort4*)(xb + (size_t)s2 * D))[lane];
        ushort4 v3 = ((const ushort4*)(xb + (size_t)s3 * D))[lane];
        acc.x += (BF2F(v0.x) + BF2F(v1.x)) + (BF2F(v2.x) + BF2F(v3.x));
        acc.y += (BF2F(v0.y) + BF2F(v1.y)) + (BF2F(v2.y) + BF2F(v3.y));
        acc.z += (BF2F(v0.z) + BF2F(v1.z)) + (BF2F(v2.z) + BF2F(v3.z));
        acc.w += (BF2F(v0.w) + BF2F(v1.w)) + (BF2F(v2.w) + BF2F(v3.w));
    }
    for (; j < end; ++j) {
        ushort4 v0 = ((const ushort4*)(xb + (size_t)csr[j] * D))[lane];
        acc.x += BF2F(v0.x); acc.y += BF2F(v0.y);
        acc.z += BF2F(v0.z); acc.w += BF2F(v0.w);
    }
    #undef BF2F
    ((float4*)(agg + (size_t)node * D))[lane] = acc;
}

// ---------------------------------------------------------------------------
// fp32 GEMM  out[n][j] = act( in[n][k] * W[k][j] + bias[j] )   (unchanged)
// ---------------------------------------------------------------------------
__global__ __launch_bounds__(256, 2) void mlp_gemm(
    const float* in_a, const float* __restrict__ in_b,
    const float* __restrict__ epsp, const float* __restrict__ W,
    const float* __restrict__ bias, float* out, int do_relu)
{
    __shared__ float Wl[D * D];                 // 64 KB
    __shared__ float inT[D * NODES_PER_BLOCK];  // 16 KB, layout [k][n]

    int tid = threadIdx.x;
    int node0 = blockIdx.x * NODES_PER_BLOCK;

    for (int i = tid; i < D * D / 4; i += 256)
        ((float4*)Wl)[i] = ((const float4*)W)[i];

    float ep = in_b ? (1.0f + epsp[0]) : 0.0f;
    for (int i = tid; i < NODES_PER_BLOCK * D / 4; i += 256) {
        int n  = i >> 5;
        int k4 = i & 31;
        const float4* pa = (const float4*)(in_a + (long long)(node0 + n) * D);
        float4 v = pa[k4];
        if (in_b) {
            const float4* pb = (const float4*)(in_b + (long long)(node0 + n) * D);
            float4 g = pb[k4];
            v.x = ep * v.x + g.x;  v.y = ep * v.y + g.y;
            v.z = ep * v.z + g.z;  v.w = ep * v.w + g.w;
        }
        int k = k4 * 4;
        inT[(k + 0) * NODES_PER_BLOCK + n] = v.x;
        inT[(k + 1) * NODES_PER_BLOCK + n] = v.y;
        inT[(k + 2) * NODES_PER_BLOCK + n] = v.z;
        inT[(k + 3) * NODES_PER_BLOCK + n] = v.w;
    }
    __syncthreads();

    int cg = tid & 31;
    int ng = tid >> 5;

    float acc[4][4];
    #pragma unroll
    for (int n = 0; n < 4; ++n)
        #pragma unroll
        for (int c = 0; c < 4; ++c) acc[n][c] = 0.0f;

    #pragma unroll 4
    for (int k = 0; k < D; ++k) {
        float4 w = *(const float4*)&Wl[k * D + cg * 4];
        float4 a = *(const float4*)&inT[k * NODES_PER_BLOCK + ng * 4];
        acc[0][0] += a.x * w.x; acc[0][1] += a.x * w.y;
        acc[0][2] += a.x * w.z; acc[0][3] += a.x * w.w;
        acc[1][0] += a.y * w.x; acc[1][1] += a.y * w.y;
        acc[1][2] += a.y * w.z; acc[1][3] += a.y * w.w;
        acc[2][0] += a.z * w.x; acc[2][1] += a.z * w.y;
        acc[2][2] += a.z * w.z; acc[2][3] += a.z * w.w;
        acc[3][0] += a.w * w.x; acc[3][1] += a.w * w.y;
        acc[3][2] += a.w * w.z; acc[3][3] += a.w * w.w;
    }

    float4 b = ((const float4*)bias)[cg];
    #pragma unroll
    for (int n = 0; n < 4; ++n) {
        float4 r;
        r.x = acc[n][0] + b.x;  r.y = acc[n][1] + b.y;
        r.z = acc[n][2] + b.z;  r.w = acc[n][3] + b.w;
        if (do_relu) {
            r.x = fmaxf(r.x, 0.0f); r.y = fmaxf(r.y, 0.0f);
            r.z = fmaxf(r.z, 0.0f); r.w = fmaxf(r.w, 0.0f);
        }
        ((float4*)(out + (long long)(node0 + ng * 4 + n) * D))[cg] = r;
    }
}

extern "C" void kernel_launch(void* const* d_in, const int* in_sizes, int n_in,
                              void* d_out, int out_size, void* d_ws, size_t ws_size,
                              hipStream_t stream) {
    const float* x   = (const float*)d_in[0];
    const int*   ei  = (const int*)d_in[1];    // edge_index [2][E]
    const float* eps = (const float*)d_in[2];
    const float* W1  = (const float*)d_in[3];
    const float* b1  = (const float*)d_in[4];
    const float* W2  = (const float*)d_in[5];
    const float* b2  = (const float*)d_in[6];
    float* out = (float*)d_out;

    int E = in_sizes[1] / 2;                   // 1,600,000
    int N = in_sizes[0] / D;                   // 100,000
    int sliceSize = (N + NSLICE - 1) / NSLICE; // 12,500

    // workspace layout (bytes, all 16B-aligned):
    //   [0, 400000)            deg   int[N]
    //   [400000, 800000)       rs    int[N]
    //   [800000, 801024)       part  int[NB]
    //   [801024, 7201024)      csr   int[E]
    //   [7201024, +N*D*4)      agg   float[N*D]          (51.2 MB)
    //   [58401024, +N*D*2)     xb    ushort[N*D] (bf16)  (25.6 MB)
    char* ws = (char*)d_ws;
    int* deg   = (int*)(ws);
    int* rs    = (int*)(ws + 400000);
    int* part  = (int*)(ws + 800000);
    int* csr   = (int*)(ws + 801024);
    float* agg = (float*)(ws + 7201024);
    unsigned short* xb = (unsigned short*)(ws + 7201024 + (size_t)N * D * 4);

    hipMemsetAsync(deg, 0, (size_t)N * sizeof(int), stream);

    int total4 = N * D / 4;                    // 3.2M float4s
    convert_kernel<<<(total4 + 255) / 256, 256, 0, stream>>>(x, xb, total4);

    int eblocks = (E + 255) / 256;             // 6250
    hist_kernel<<<eblocks * NSLICE, 256, 0, stream>>>(ei, deg, E, sliceSize);

    int NB = (N + SCAN_CHUNK - 1) / SCAN_CHUNK;  // 98
    scan_blocksums<<<NB, 256, 0, stream>>>(deg, part, N);
    scan_partials<<<1, 64, 0, stream>>>(part, NB);
    scan_final<<<NB, 256, 0, stream>>>(deg, part, rs, N);

    fill_kernel<<<eblocks * NSLICE, 256, 0, stream>>>(ei, rs, csr, E, sliceSize);

    int gblocks_gather = (N + 7) / 8;          // 12500 (8 nodes/block)
    gather_kernel<<<gblocks_gather, 256, 0, stream>>>(xb, rs, csr, agg, N);

    int gblocks = N / NODES_PER_BLOCK;         // 3125
    mlp_gemm<<<gblocks, 256, 0, stream>>>(x, agg, eps, W1, b1, out, 1);
    mlp_gemm<<<gblocks, 256, 0, stream>>>(out, nullptr, eps, W2, b2, out, 0);
}

// Round 6
// 382.146 us; speedup vs baseline: 7.7238x; 1.2618x over previous
//
#include <hip/hip_runtime.h>

#define D 128
#define SCAN_CHUNK 1024   // elements per scan block (256 threads x int4)
#define NSLICE 8          // XCD count: blockIdx%8 -> XCD (perf heuristic)
#define LDSPITCH 136      // ushorts/row: 128+8 pad (272B = 68 words, 68%32=4 -> 2-way=free)

typedef __attribute__((ext_vector_type(8))) short bf16x8;   // 8 bf16 = 4 VGPR
typedef __attribute__((ext_vector_type(4))) float f32x4;    // MFMA acc

__device__ __forceinline__ unsigned short f2bf(float f) {   // fp32 -> bf16 RNE
    union { float f; unsigned int u; } c; c.f = f;
    return (unsigned short)((c.u + 0x7FFFu + ((c.u >> 16) & 1u)) >> 16);
}

// ---------------------------------------------------------------------------
// x (fp32) -> xb (bf16) for the gather.
// ---------------------------------------------------------------------------
__global__ __launch_bounds__(256) void convert_kernel(
    const float* __restrict__ x, unsigned short* __restrict__ xb, int total4)
{
    int gid = blockIdx.x * 256 + threadIdx.x;
    if (gid >= total4) return;
    float4 v = ((const float4*)x)[gid];
    ushort4 o;
    o.x = f2bf(v.x); o.y = f2bf(v.y); o.z = f2bf(v.z); o.w = f2bf(v.w);
    ((ushort4*)xb)[gid] = o;
}

// ---------------------------------------------------------------------------
// W [k][n] fp32 -> Wt [n][k] bf16 (transposed so B-frags are 16B-contiguous).
// 16384 threads, tiny.
// ---------------------------------------------------------------------------
__global__ __launch_bounds__(256) void convw_kernel(
    const float* __restrict__ W, unsigned short* __restrict__ Wt)
{
    int gid = blockIdx.x * 256 + threadIdx.x;   // 0..16383
    int n = gid >> 7, k = gid & 127;
    Wt[n * 128 + k] = f2bf(W[k * 128 + n]);
}

// ---------------------------------------------------------------------------
// CSR step 1: degree histogram, XCD-sliced.
// ---------------------------------------------------------------------------
__global__ __launch_bounds__(256) void hist_kernel(
    const int* __restrict__ ei, int* __restrict__ deg, int E, int sliceSize)
{
    int slice = blockIdx.x & (NSLICE - 1);
    int gid = (blockIdx.x >> 3) * 256 + threadIdx.x;
    if (gid >= E) return;
    int d = ei[E + gid];
    int lo = slice * sliceSize;
    if (d < lo || d >= lo + sliceSize) return;
    atomicAdd(&deg[d], 1);
}

// ---------------------------------------------------------------------------
// Scan phase A: per-block sums of deg.
// ---------------------------------------------------------------------------
__global__ __launch_bounds__(256) void scan_blocksums(
    const int* __restrict__ deg, int* __restrict__ part, int N)
{
    int tid = threadIdx.x;
    int idx = blockIdx.x * SCAN_CHUNK + tid * 4;
    int s = 0;
    if (idx < N) {
        int4 v = *(const int4*)(deg + idx);
        s = v.x + v.y + v.z + v.w;
    }
    #pragma unroll
    for (int off = 32; off > 0; off >>= 1) s += __shfl_down(s, off);
    __shared__ int ws[4];
    int wave = tid >> 6, lane = tid & 63;
    if (lane == 0) ws[wave] = s;
    __syncthreads();
    if (tid == 0) part[blockIdx.x] = ws[0] + ws[1] + ws[2] + ws[3];
}

// ---------------------------------------------------------------------------
// Scan phase B: one wave scans the NB partials in-place (-> exclusive).
// ---------------------------------------------------------------------------
__global__ __launch_bounds__(64) void scan_partials(int* part, int NB)
{
    int lane = threadIdx.x;
    int carry = 0;
    for (int base = 0; base < NB; base += 64) {
        int i = base + lane;
        int v = (i < NB) ? part[i] : 0;
        int sc = v;
        #pragma unroll
        for (int off = 1; off < 64; off <<= 1) {
            int t = __shfl_up(sc, off);
            if (lane >= off) sc += t;
        }
        if (i < NB) part[i] = carry + sc - v;
        carry += __shfl(sc, 63);
    }
}

// ---------------------------------------------------------------------------
// Scan phase C: block-level exclusive scan + block offset -> rs.
// ---------------------------------------------------------------------------
__global__ __launch_bounds__(256) void scan_final(
    const int* __restrict__ deg, const int* __restrict__ part,
    int* __restrict__ rs, int N)
{
    int tid = threadIdx.x;
    int idx = blockIdx.x * SCAN_CHUNK + tid * 4;
    int4 v = make_int4(0, 0, 0, 0);
    if (idx < N) v = *(const int4*)(deg + idx);
    int s = v.x + v.y + v.z + v.w;

    int lane = tid & 63, wave = tid >> 6;
    int sc = s;
    #pragma unroll
    for (int off = 1; off < 64; off <<= 1) {
        int t = __shfl_up(sc, off);
        if (lane >= off) sc += t;
    }
    __shared__ int ws[4];
    if (lane == 63) ws[wave] = sc;
    __syncthreads();
    int woff = 0;
    #pragma unroll
    for (int w = 0; w < 4; ++w) if (w < wave) woff += ws[w];

    if (idx < N) {
        int ex = part[blockIdx.x] + woff + (sc - s);
        int4 o;
        o.x = ex;
        o.y = o.x + v.x;
        o.z = o.y + v.y;
        o.w = o.z + v.z;
        *(int4*)(rs + idx) = o;
    }
}

// ---------------------------------------------------------------------------
// CSR step 3: fill, XCD-sliced.  After: rs[n] == inclusive prefix.
// ---------------------------------------------------------------------------
__global__ __launch_bounds__(256) void fill_kernel(
    const int* __restrict__ ei, int* __restrict__ rs,
    int* __restrict__ csr, int E, int sliceSize)
{
    int slice = blockIdx.x & (NSLICE - 1);
    int gid = (blockIdx.x >> 3) * 256 + threadIdx.x;
    if (gid >= E) return;
    int d = ei[E + gid];
    int lo = slice * sliceSize;
    if (d < lo || d >= lo + sliceSize) return;
    int s = ei[gid];
    int pos = atomicAdd(&rs[d], 1);
    csr[pos] = s;
}

// ---------------------------------------------------------------------------
// Gather + GIN combine: acc = sum_j xb[src_j]; u = (1+eps)*x[node] + acc,
// written bf16 to ub.  32 lanes/node, ushort4/lane, fp32 accumulate.
// ---------------------------------------------------------------------------
__global__ __launch_bounds__(256) void gather_kernel(
    const unsigned short* __restrict__ xb, const float* __restrict__ x,
    const float* __restrict__ epsp, const int* __restrict__ rs,
    const int* __restrict__ csr, unsigned short* __restrict__ ub, int N)
{
    int sub  = threadIdx.x >> 5;
    int lane = threadIdx.x & 31;
    int node = blockIdx.x * 8 + sub;
    if (node >= N) return;

    int start = (node == 0) ? 0 : rs[node - 1];
    int end   = rs[node];

    float4 acc = make_float4(0.f, 0.f, 0.f, 0.f);
    union { unsigned int u; float f; } c;
    #define BF2F(us) (c.u = ((unsigned int)(us)) << 16, c.f)

    int j = start;
    for (; j + 3 < end; j += 4) {
        int s0 = csr[j], s1 = csr[j + 1], s2 = csr[j + 2], s3 = csr[j + 3];
        ushort4 v0 = ((const ushort4*)(xb + (size_t)s0 * D))[lane];
        ushort4 v1 = ((const ushort4*)(xb + (size_t)s1 * D))[lane];
        ushort4 v2 = ((const ushort4*)(xb + (size_t)s2 * D))[lane];
        ushort4 v3 = ((const ushort4*)(xb + (size_t)s3 * D))[lane];
        acc.x += (BF2F(v0.x) + BF2F(v1.x)) + (BF2F(v2.x) + BF2F(v3.x));
        acc.y += (BF2F(v0.y) + BF2F(v1.y)) + (BF2F(v2.y) + BF2F(v3.y));
        acc.z += (BF2F(v0.z) + BF2F(v1.z)) + (BF2F(v2.z) + BF2F(v3.z));
        acc.w += (BF2F(v0.w) + BF2F(v1.w)) + (BF2F(v2.w) + BF2F(v3.w));
    }
    for (; j < end; ++j) {
        ushort4 v0 = ((const ushort4*)(xb + (size_t)csr[j] * D))[lane];
        acc.x += BF2F(v0.x); acc.y += BF2F(v0.y);
        acc.z += BF2F(v0.z); acc.w += BF2F(v0.w);
    }
    #undef BF2F

    // GIN combine: u = (1+eps)*x + agg   (x read fp32 for accuracy)
    float ep1 = 1.0f + epsp[0];
    float4 xr = ((const float4*)(x + (size_t)node * D))[lane];
    acc.x = fmaf(ep1, xr.x, acc.x);
    acc.y = fmaf(ep1, xr.y, acc.y);
    acc.z = fmaf(ep1, xr.z, acc.z);
    acc.w = fmaf(ep1, xr.w, acc.w);
    ushort4 o;
    o.x = f2bf(acc.x); o.y = f2bf(acc.y); o.z = f2bf(acc.z); o.w = f2bf(acc.w);
    ((ushort4*)(ub + (size_t)node * D))[lane] = o;
}

// ---------------------------------------------------------------------------
// bf16 MFMA GEMM: out[n][:] = act( in[n][k] @ W[k][:] + bias ).
// 64 rows/block, 4 waves; wave w owns rows w*16..w*16+15, all 128 cols as
// 8 col-tiles of mfma_f32_16x16x32_bf16 (K-loop = 4).
// A-frag: A[m=lane&15][k=quad*8+j]; B-frag from Wt[n][k] (pre-transposed);
// C/D: col=lane&15, row=quad*4+reg  [m89-verified].
// LDS rows padded to 136 ushorts -> 2-way bank aliasing only (free).
// relu_bf16=1: relu + bf16 out (layer 1) ; 0: fp32 out (layer 2).
// ---------------------------------------------------------------------------
__global__ __launch_bounds__(256, 2) void mfma_gemm(
    const unsigned short* __restrict__ in, const unsigned short* __restrict__ Wt,
    const float* __restrict__ bias, void* __restrict__ outp,
    int N, int relu_bf16)
{
    __shared__ unsigned short Wl[128 * LDSPITCH];  // 34816 B
    __shared__ unsigned short Al[64 * LDSPITCH];   // 17408 B

    int tid = threadIdx.x;
    int row0 = blockIdx.x * 64;

    for (int i = tid; i < 128 * 16; i += 256) {            // stage Wt
        int r = i >> 4, cc = i & 15;
        ((int4*)(Wl + r * LDSPITCH))[cc] = ((const int4*)(Wt + r * 128))[cc];
    }
    for (int i = tid; i < 64 * 16; i += 256) {             // stage A (zero-pad)
        int r = i >> 4, cc = i & 15;
        int4 v = make_int4(0, 0, 0, 0);
        if (row0 + r < N) v = ((const int4*)(in + (size_t)(row0 + r) * 128))[cc];
        ((int4*)(Al + r * LDSPITCH))[cc] = v;
    }
    __syncthreads();

    int wave = tid >> 6, lane = tid & 63;
    int l16 = lane & 15, lq = lane >> 4;

    f32x4 acc[8];
    #pragma unroll
    for (int t = 0; t < 8; ++t) acc[t] = (f32x4){0.f, 0.f, 0.f, 0.f};

    int arow = wave * 16 + l16;
    #pragma unroll
    for (int kk = 0; kk < 4; ++kk) {
        int k0 = kk * 32 + lq * 8;
        bf16x8 a = *(const bf16x8*)(Al + arow * LDSPITCH + k0);
        #pragma unroll
        for (int t = 0; t < 8; ++t) {
            bf16x8 b = *(const bf16x8*)(Wl + (t * 16 + l16) * LDSPITCH + k0);
            acc[t] = __builtin_amdgcn_mfma_f32_16x16x32_bf16(a, b, acc[t], 0, 0, 0);
        }
    }

    #pragma unroll
    for (int t = 0; t < 8; ++t) {
        int col = t * 16 + l16;
        float bv = bias[col];
        #pragma unroll
        for (int r = 0; r < 4; ++r) {
            int row = row0 + wave * 16 + lq * 4 + r;
            if (row >= N) continue;
            float v = acc[t][r] + bv;
            if (relu_bf16) {
                v = fmaxf(v, 0.0f);
                ((unsigned short*)outp)[(size_t)row * 128 + col] = f2bf(v);
            } else {
                ((float*)outp)[(size_t)row * 128 + col] = v;
            }
        }
    }
}

extern "C" void kernel_launch(void* const* d_in, const int* in_sizes, int n_in,
                              void* d_out, int out_size, void* d_ws, size_t ws_size,
                              hipStream_t stream) {
    const float* x   = (const float*)d_in[0];
    const int*   ei  = (const int*)d_in[1];    // edge_index [2][E]
    const float* eps = (const float*)d_in[2];
    const float* W1  = (const float*)d_in[3];
    const float* b1  = (const float*)d_in[4];
    const float* W2  = (const float*)d_in[5];
    const float* b2  = (const float*)d_in[6];
    float* out = (float*)d_out;

    int E = in_sizes[1] / 2;                   // 1,600,000
    int N = in_sizes[0] / D;                   // 100,000
    int sliceSize = (N + NSLICE - 1) / NSLICE; // 12,500

    // workspace layout (bytes):
    //   [0, 400000)              deg  int[N]
    //   [400000, 800000)         rs   int[N]
    //   [800000, 801024)         part int[NB]
    //   [801024, 7201024)        csr  int[E]
    //   [7201024, 32801024)      xb   bf16[N*D]  -- reused as hb after gather
    //   [32801024, 58401024)     ub   bf16[N*D]
    //   [58401024, 58433792)     W1t  bf16[128*128]
    //   [58433792, 58466560)     W2t  bf16[128*128]
    char* ws = (char*)d_ws;
    int* deg   = (int*)(ws);
    int* rs    = (int*)(ws + 400000);
    int* part  = (int*)(ws + 800000);
    int* csr   = (int*)(ws + 801024);
    unsigned short* xb  = (unsigned short*)(ws + 7201024);
    unsigned short* hb  = xb;   // safe: xb dead after gather, stream-ordered
    unsigned short* ub  = (unsigned short*)(ws + 32801024);
    unsigned short* W1t = (unsigned short*)(ws + 58401024);
    unsigned short* W2t = (unsigned short*)(ws + 58433792);

    hipMemsetAsync(deg, 0, (size_t)N * sizeof(int), stream);

    int total4 = N * D / 4;
    convert_kernel<<<(total4 + 255) / 256, 256, 0, stream>>>(x, xb, total4);
    convw_kernel<<<64, 256, 0, stream>>>(W1, W1t);
    convw_kernel<<<64, 256, 0, stream>>>(W2, W2t);

    int eblocks = (E + 255) / 256;
    hist_kernel<<<eblocks * NSLICE, 256, 0, stream>>>(ei, deg, E, sliceSize);

    int NB = (N + SCAN_CHUNK - 1) / SCAN_CHUNK;
    scan_blocksums<<<NB, 256, 0, stream>>>(deg, part, N);
    scan_partials<<<1, 64, 0, stream>>>(part, NB);
    scan_final<<<NB, 256, 0, stream>>>(deg, part, rs, N);

    fill_kernel<<<eblocks * NSLICE, 256, 0, stream>>>(ei, rs, csr, E, sliceSize);

    gather_kernel<<<(N + 7) / 8, 256, 0, stream>>>(xb, x, eps, rs, csr, ub, N);

    int gemm_blocks = (N + 63) / 64;           // 1563
    mfma_gemm<<<gemm_blocks, 256, 0, stream>>>(ub, W1t, b1, (void*)hb, N, 1);
    mfma_gemm<<<gemm_blocks, 256, 0, stream>>>(hb, W2t, b2, (void*)out, N, 0);
}